// Round 1
// baseline (334.988 us; speedup 1.0000x reference)
//
#include <hip/hip_runtime.h>
#include <math.h>

// ---------------------------------------------------------------------------
// ByteMultiHeadSelfAttention: B=2 S=2048 E=2048, H=16 KV=4 D=128, RoPE, causal.
//   convx:     x fp32 -> xb bf16
//   wconv_all: Wq|Wk|Wv|Wo fp32 (K,N) -> bf16 (N,K), one launch
//   gemm_bt:   qkv = xb @ Wqkv (bf16)  [DMA double-buffer, single barrier/iter]
//   rope:      Q[B,H,S,D] (pre-scaled by 1/sqrt(D)*log2e), K[B,KV,S,D]
//   vtrans:    Vt[B,KV,D,S]
//   flash2:    32x32 MFMA, swapped QK^T, in-register P (cvt_pk+permlane32_swap),
//              fixed-max softmax, DMA double-buffer, Q-tile 128/block
//   gemm_bt:   out = attn @ Wo (fp32)
// ---------------------------------------------------------------------------

typedef __attribute__((ext_vector_type(8))) short short8;
typedef __attribute__((ext_vector_type(4))) float f32x4;
typedef __attribute__((ext_vector_type(16))) float f32x16;

typedef const __attribute__((address_space(1))) void* gvp;
typedef __attribute__((address_space(3))) void* svp;

__device__ __forceinline__ void async16(const void* g, void* l) {
  __builtin_amdgcn_global_load_lds((gvp)g, (svp)l, 16, 0, 0);
}
__device__ __forceinline__ void wait_vm0() { asm volatile("s_waitcnt vmcnt(0)" ::: "memory"); }
__device__ __forceinline__ void barrier_raw() { asm volatile("s_barrier" ::: "memory"); }

__device__ __forceinline__ unsigned short f2b(float f) {
  unsigned int u = __builtin_bit_cast(unsigned int, f);
  u += 0x7fffu + ((u >> 16) & 1u);   // RNE
  return (unsigned short)(u >> 16);
}
__device__ __forceinline__ float b2f(unsigned short h) {
  unsigned int u = ((unsigned int)h) << 16;
  return __builtin_bit_cast(float, u);
}

// packed f32->bf16 (RNE, same as f2b) — one instr for two values
__device__ __forceinline__ unsigned int pk_bf16(float a, float b) {
  unsigned int r;
  asm("v_cvt_pk_bf16_f32 %0, %1, %2" : "=v"(r) : "v"(a), "v"(b));
  return r;
}
// exchange a[32..63] <-> b[0..31]
__device__ __forceinline__ void plswap(unsigned int& a, unsigned int& b) {
  asm("v_permlane32_swap_b32 %0, %1" : "+v"(a), "+v"(b));
}

// ---------------- x -> bf16 ----------------
__global__ __launch_bounds__(256) void convx(const float* __restrict__ x,
                                             unsigned short* __restrict__ xb) {
  int i = blockIdx.x * 256 + threadIdx.x;
  const float4* p = (const float4*)x + (size_t)i * 2;
  float4 a = p[0], b4 = p[1];
  union { short8 v; unsigned short u[8]; } o;
  o.u[0] = f2b(a.x);  o.u[1] = f2b(a.y);  o.u[2] = f2b(a.z);  o.u[3] = f2b(a.w);
  o.u[4] = f2b(b4.x); o.u[5] = f2b(b4.y); o.u[6] = f2b(b4.z); o.u[7] = f2b(b4.w);
  ((short8*)xb)[i] = o.v;
}

// ---------------- all W (K,N) fp32 -> WT (N,K) bf16, one launch ----------------
__global__ __launch_bounds__(256) void wconv_all(const float* __restrict__ Wq,
                                                 const float* __restrict__ Wk,
                                                 const float* __restrict__ Wv,
                                                 const float* __restrict__ Wo,
                                                 unsigned short* __restrict__ WqkvT,
                                                 unsigned short* __restrict__ WoT) {
  __shared__ float t[32][33];
  int idx = blockIdx.x;
  const float* W; unsigned short* WT; int N, tx, ty;
  const int K = 2048;
  if (idx < 4096)      { W = Wq; WT = WqkvT;                         N = 2048; idx -= 0;    tx = idx & 63; ty = idx >> 6; }
  else if (idx < 5120) { W = Wk; WT = WqkvT + (size_t)2048 * 2048;   N = 512;  idx -= 4096; tx = idx & 15; ty = idx >> 4; }
  else if (idx < 6144) { W = Wv; WT = WqkvT + (size_t)2560 * 2048;   N = 512;  idx -= 5120; tx = idx & 15; ty = idx >> 4; }
  else                 { W = Wo; WT = WoT;                           N = 2048; idx -= 6144; tx = idx & 63; ty = idx >> 6; }
  int c = threadIdx.x & 31, r0 = threadIdx.x >> 5;
  int k0 = ty * 32, n0 = tx * 32;
#pragma unroll
  for (int r = r0; r < 32; r += 8) t[r][c] = W[(size_t)(k0 + r) * N + n0 + c];
  __syncthreads();
#pragma unroll
  for (int r = r0; r < 32; r += 8) WT[(size_t)(n0 + r) * K + k0 + c] = f2b(t[c][r]);
}

// ---------------- GEMM: C[M,N] = A[M,K] * BT[N,K]^T ----------------
__global__ __launch_bounds__(256) void gemm_bt(const unsigned short* __restrict__ A,
                                               const unsigned short* __restrict__ BT,
                                               void* __restrict__ Cout,
                                               int M, int N, int K, int out_bf16) {
  const int n0 = blockIdx.x * 128;
  const int m0 = blockIdx.y * 128;
  const int tid = threadIdx.x;
  const int w = tid >> 6, lane = tid & 63, l15 = lane & 15, quad = lane >> 4;
  const int wm = w >> 1, wn = w & 1;

  __shared__ __align__(16) unsigned short As[2][128 * 64];
  __shared__ __align__(16) unsigned short Bs[2][128 * 64];

  f32x4 acc[4][4];
#pragma unroll
  for (int mi = 0; mi < 4; mi++)
#pragma unroll
    for (int ni = 0; ni < 4; ni++) acc[mi][ni] = (f32x4){0.f, 0.f, 0.f, 0.f};

  const int rl = lane >> 3;
  const int cl = lane & 7;
  const unsigned short* Ab = A + (size_t)m0 * K;
  const unsigned short* Bb = BT + (size_t)n0 * K;

#pragma unroll
  for (int i = 0; i < 4; i++) {
    int row = w * 32 + i * 8 + rl;
    int gc = cl ^ (row & 7);
    async16(Ab + (size_t)row * K + gc * 8, &As[0][(w * 32 + i * 8) * 64]);
    async16(Bb + (size_t)row * K + gc * 8, &Bs[0][(w * 32 + i * 8) * 64]);
  }

  const int nIter = K >> 6;
  for (int j = 0; j < nIter; j++) {
    wait_vm0();
    barrier_raw();
    const int cur = j & 1;

    if (j + 1 < nIter) {
      int kb = (j + 1) * 64;
#pragma unroll
      for (int i = 0; i < 4; i++) {
        int row = w * 32 + i * 8 + rl;
        int gc = cl ^ (row & 7);
        async16(Ab + (size_t)row * K + kb + gc * 8, &As[cur ^ 1][(w * 32 + i * 8) * 64]);
        async16(Bb + (size_t)row * K + kb + gc * 8, &Bs[cur ^ 1][(w * 32 + i * 8) * 64]);
      }
    }

    const unsigned short* as = &As[cur][0];
    const unsigned short* bs = &Bs[cur][0];
#pragma unroll
    for (int kk = 0; kk < 2; kk++) {
      short8 af[4], bfv[4];
#pragma unroll
      for (int mi = 0; mi < 4; mi++) {
        int row = wm * 64 + mi * 16 + l15;
        af[mi] = *(const short8*)&as[row * 64 + (((kk * 4 + quad) ^ (row & 7)) * 8)];
      }
#pragma unroll
      for (int ni = 0; ni < 4; ni++) {
        int row = wn * 64 + ni * 16 + l15;
        bfv[ni] = *(const short8*)&bs[row * 64 + (((kk * 4 + quad) ^ (row & 7)) * 8)];
      }
#pragma unroll
      for (int mi = 0; mi < 4; mi++)
#pragma unroll
        for (int ni = 0; ni < 4; ni++)
          acc[mi][ni] = __builtin_amdgcn_mfma_f32_16x16x32_bf16(af[mi], bfv[ni],
                                                                acc[mi][ni], 0, 0, 0);
    }
  }

  if (out_bf16) {
    unsigned short* C = (unsigned short*)Cout;
#pragma unroll
    for (int mi = 0; mi < 4; mi++)
#pragma unroll
      for (int ni = 0; ni < 4; ni++)
#pragma unroll
        for (int r = 0; r < 4; r++) {
          int row = m0 + wm * 64 + mi * 16 + quad * 4 + r;
          int col = n0 + wn * 64 + ni * 16 + l15;
          C[(size_t)row * N + col] = f2b(acc[mi][ni][r]);
        }
  } else {
    float* C = (float*)Cout;
#pragma unroll
    for (int mi = 0; mi < 4; mi++)
#pragma unroll
      for (int ni = 0; ni < 4; ni++)
#pragma unroll
        for (int r = 0; r < 4; r++) {
          int row = m0 + wm * 64 + mi * 16 + quad * 4 + r;
          int col = n0 + wn * 64 + ni * 16 + l15;
          C[(size_t)row * N + col] = acc[mi][ni][r];
        }
  }
}

// ---------------- RoPE (Q pre-scaled by 1/sqrt(128)*log2(e)) ----------------
#define SC_TOT 0.12753785056274918f
__global__ __launch_bounds__(256) void rope_kernel(const unsigned short* __restrict__ qkv,
                                                   unsigned short* __restrict__ Q,
                                                   unsigned short* __restrict__ Kd) {
  int b = blockIdx.z, hh = blockIdx.y;
  int tid = threadIdx.x;
  int d = tid & 63, sl = tid >> 6;
  int s = blockIdx.x * 4 + sl;
  const unsigned short* src = qkv + ((size_t)(b * 2048 + s)) * 3072 + hh * 128;
  float lo = b2f(src[d]), hi = b2f(src[d + 64]);
  float invf = exp2f(-0.20762050593046f * (float)d);
  float ang = (float)s * invf;
  float sn, cs;
  sincosf(ang, &sn, &cs);
  float nlo = lo * cs - hi * sn;
  float nhi = hi * cs + lo * sn;
  unsigned short* dst;
  if (hh < 16) {
    nlo *= SC_TOT; nhi *= SC_TOT;
    dst = Q + ((size_t)((b * 16 + hh) * 2048 + s)) * 128;
  } else {
    dst = Kd + ((size_t)((b * 4 + (hh - 16)) * 2048 + s)) * 128;
  }
  dst[d] = f2b(nlo);
  dst[d + 64] = f2b(nhi);
}

// ---------------- V transpose ----------------
__global__ __launch_bounds__(256) void vtrans(const unsigned short* __restrict__ qkv,
                                              unsigned short* __restrict__ Vt) {
  int bkv = blockIdx.z;
  int b = bkv >> 2, kv = bkv & 3;
  int s0 = blockIdx.x * 64, d0 = blockIdx.y * 64;
  __shared__ unsigned short t[64][65];
  int c = threadIdx.x & 63, r0 = threadIdx.x >> 6;
  const unsigned short* src = qkv + ((size_t)(b * 2048 + s0)) * 3072 + 2560 + kv * 128 + d0;
#pragma unroll
  for (int r = r0; r < 64; r += 4) t[r][c] = src[(size_t)r * 3072 + c];
  __syncthreads();
  unsigned short* dst = Vt + ((size_t)bkv * 128 + d0) * 2048 + s0;
#pragma unroll
  for (int r = r0; r < 64; r += 4) dst[(size_t)r * 2048 + c] = t[c][r];
}

// ---------------- Flash attention: 32x32 MFMA, in-register P ----------------
#define FIXED_M 12.0f

// Process one 32(kv)x32(q) S^T accumulator: softmax (fixed max), causal mask,
// l accumulation, and repack into two PV A-fragments (kv 16 each) via
// cvt_pk + permlane32_swap (T12). kvb already includes +4*hi.
__device__ __forceinline__ void proc_acc(const f32x16& s, bool msk, int kvb, int q,
                                         float& l_own, short8& paL, short8& paH) {
  float p[16];
#pragma unroll
  for (int r = 0; r < 16; r++) {
    float v = exp2f(s[r] - FIXED_M);
    if (msk) {
      int kv = kvb + (r & 3) + 8 * (r >> 2);
      if (kv > q) v = 0.f;
    }
    p[r] = v;
    l_own += v;
  }
  unsigned int u0 = pk_bf16(p[0], p[1]),  u1 = pk_bf16(p[2], p[3]);
  unsigned int u2 = pk_bf16(p[4], p[5]),  u3 = pk_bf16(p[6], p[7]);
  plswap(u0, u2); plswap(u1, u3);
  unsigned int w0 = pk_bf16(p[8], p[9]),  w1 = pk_bf16(p[10], p[11]);
  unsigned int w2 = pk_bf16(p[12], p[13]), w3 = pk_bf16(p[14], p[15]);
  plswap(w0, w2); plswap(w1, w3);
  union { unsigned int u[4]; short8 s8; } a, b;
  a.u[0] = u0; a.u[1] = u1; a.u[2] = u2; a.u[3] = u3;
  b.u[0] = w0; b.u[1] = w1; b.u[2] = w2; b.u[3] = w3;
  paL = a.s8; paH = b.s8;
}

__global__ __launch_bounds__(256, 2) void flash2(const unsigned short* __restrict__ Q,
                                                 const unsigned short* __restrict__ Kc,
                                                 const unsigned short* __restrict__ Vt,
                                                 unsigned short* __restrict__ attn) {
  const int qt = 15 - blockIdx.x;      // largest blocks first (LPT)
  const int h = blockIdx.y;
  const int b = blockIdx.z;
  const int kvh = h >> 2;
  const int tid = threadIdx.x;
  const int w = tid >> 6, lane = tid & 63;
  const int l31 = lane & 31, hi = lane >> 5, x7 = l31 & 7;

  __shared__ __align__(16) unsigned short kbuf[2][64 * 128];   // [kv][d] swz
  __shared__ __align__(16) unsigned short vbuf[2][128 * 64];   // [d][s]  swz
  __shared__ __align__(16) float li[4][32];

  const unsigned short* Qb = Q  + ((size_t)(b * 16 + h)) * 2048 * 128;
  const unsigned short* Kb = Kc + ((size_t)(b * 4 + kvh)) * 2048 * 128;
  const unsigned short* Vb = Vt + ((size_t)(b * 4 + kvh)) * 128 * 2048;

  const int q0 = qt * 128;
  const int qw = q0 + w * 32;          // wave's q base (32 rows)
  const int qv = qw + l31;             // this lane's q row
  const int nT = 2 * qt + 2;

  // Q fragments: qf[s] = Q[qv][s*16 + hi*8 .. +7]
  short8 qf[8];
  {
    const unsigned short* qp = Qb + (size_t)qv * 128 + hi * 8;
#pragma unroll
    for (int s = 0; s < 8; s++) qf[s] = *(const short8*)(qp + s * 16);
  }

  f32x16 o[4];
#pragma unroll
  for (int d = 0; d < 4; d++)
#pragma unroll
    for (int e = 0; e < 16; e++) o[d][e] = 0.f;
  float l_own = 0.f;

  // prologue: DMA tile 0 into buf 0
#pragma unroll
  for (int k2 = 0; k2 < 4; k2++) {
    int m = w * 4 + k2;
    int rl = m * 4 + (lane >> 4);
    int c8 = (lane & 15) ^ (rl & 7);
    async16(Kb + (size_t)rl * 128 + c8 * 8, &kbuf[0][m * 512]);
  }
#pragma unroll
  for (int k2 = 0; k2 < 4; k2++) {
    int m = w * 4 + k2;
    int d = m * 8 + (lane >> 3);
    int c3 = (lane & 7) ^ (d & 7);
    async16(Vb + (size_t)d * 2048 + c3 * 8, &vbuf[0][m * 512]);
  }

  for (int j = 0; j < nT; j++) {
    wait_vm0();
    barrier_raw();
    const int cur = j & 1;
    const int kb = j * 64;

    if (j + 1 < nT) {
      int kb2 = kb + 64;
#pragma unroll
      for (int k2 = 0; k2 < 4; k2++) {
        int m = w * 4 + k2;
        int rl = m * 4 + (lane >> 4);
        int c8 = (lane & 15) ^ (rl & 7);
        async16(Kb + (size_t)(kb2 + rl) * 128 + c8 * 8, &kbuf[cur ^ 1][m * 512]);
      }
#pragma unroll
      for (int k2 = 0; k2 < 4; k2++) {
        int m = w * 4 + k2;
        int d = m * 8 + (lane >> 3);
        int c3 = (lane & 7) ^ (d & 7);
        async16(Vb + (size_t)d * 2048 + kb2 + c3 * 8, &vbuf[cur ^ 1][m * 512]);
      }
    }

    if (kb > qw + 31) continue;        // tile fully above diagonal for this wave

    // QK^T swapped: S^T[kv, q] = mfma(A=K, B=Q), two 32-kv blocks
    f32x16 sA, sB;
#pragma unroll
    for (int e = 0; e < 16; e++) { sA[e] = 0.f; sB[e] = 0.f; }
    const unsigned short* kp = &kbuf[cur][0];
#pragma unroll
    for (int s = 0; s < 8; s++) {
      int ch = (((s << 1) | hi) ^ x7) << 3;
      short8 ka = *(const short8*)&kp[l31 * 128 + ch];
      short8 kB = *(const short8*)&kp[(32 + l31) * 128 + ch];
      sA = __builtin_amdgcn_mfma_f32_32x32x16_bf16(ka, qf[s], sA, 0, 0, 0);
      sB = __builtin_amdgcn_mfma_f32_32x32x16_bf16(kB, qf[s], sB, 0, 0, 0);
    }

    const bool msk = (kb + 63 > qw);
    short8 pa[4];
    proc_acc(sA, msk, kb + 4 * hi, qv, l_own, pa[0], pa[1]);
    proc_acc(sB, msk, kb + 32 + 4 * hi, qv, l_own, pa[2], pa[3]);

    // PV: O[q, d] += P * V ; V from [d][s] LDS rows, contiguous b128 B-frags
    const unsigned short* vp = &vbuf[cur][0];
#pragma unroll
    for (int db = 0; db < 4; db++) {
      int ro = (db * 32 + l31) * 64;
#pragma unroll
      for (int f = 0; f < 4; f++) {
        int ch = (((f << 1) | hi) ^ x7) << 3;
        short8 vf = *(const short8*)&vp[ro + ch];
        o[db] = __builtin_amdgcn_mfma_f32_32x32x16_bf16(pa[f], vf, o[db], 0, 0, 0);
      }
    }
  }

  // normalize: l per q row lives at lane (q, hi) + (q, hi^1)
  float l_tot = l_own + __shfl_xor(l_own, 32);
  if (hi == 0) li[w][l31] = 1.f / l_tot;
  f32x4 inv4[4];
#pragma unroll
  for (int t = 0; t < 4; t++) inv4[t] = *(const f32x4*)&li[w][t * 8 + 4 * hi];

  // O C-layout: col(lane)=d=db*32+l31, row(reg)=(r&3)+8*(r>>2)+4*hi
  unsigned short* ap0 = attn + ((size_t)(b * 2048 + qw)) * 2048 + h * 128 + l31;
#pragma unroll
  for (int db = 0; db < 4; db++) {
#pragma unroll
    for (int r = 0; r < 16; r++) {
      int rowq = (r & 3) + 8 * (r >> 2) + 4 * hi;
      ap0[(size_t)rowq * 2048 + db * 32] = f2b(o[db][r] * inv4[r >> 2][r & 3]);
    }
  }
}

// ---------------------------------------------------------------------------
extern "C" void kernel_launch(void* const* d_in, const int* in_sizes, int n_in,
                              void* d_out, int out_size, void* d_ws, size_t ws_size,
                              hipStream_t stream) {
  const float* x  = (const float*)d_in[0];
  const float* Wq = (const float*)d_in[1];
  const float* Wk = (const float*)d_in[2];
  const float* Wv = (const float*)d_in[3];
  const float* Wo = (const float*)d_in[4];
  float* out = (float*)d_out;

  char* ws = (char*)d_ws;
  unsigned short* xb    = (unsigned short*)(ws);              // 16.78 MB (reused as attn)
  unsigned short* WqkvT = (unsigned short*)(ws + 16777216);   // 12.58 MB [3072][2048]
  unsigned short* WoT   = (unsigned short*)(ws + 29360128);   //  8.39 MB [2048][2048]
  unsigned short* qkv   = (unsigned short*)(ws + 37748736);   // 25.17 MB [4096][3072]
  unsigned short* Qm    = (unsigned short*)(ws + 62914560);   // 16.78 MB [B,H,S,D]
  unsigned short* Km    = (unsigned short*)(ws + 79691776);   //  4.19 MB [B,KV,S,D]
  unsigned short* Vtm   = (unsigned short*)(ws + 83886080);   //  4.19 MB [B,KV,D,S]
  unsigned short* attn  = xb;

  convx<<<4096, 256, 0, stream>>>(x, xb);
  wconv_all<<<10240, 256, 0, stream>>>(Wq, Wk, Wv, Wo, WqkvT, WoT);

  gemm_bt<<<dim3(24, 32), 256, 0, stream>>>(xb, WqkvT, qkv, 4096, 3072, 2048, 1);

  rope_kernel<<<dim3(512, 20, 2), 256, 0, stream>>>(qkv, Qm, Km);
  vtrans<<<dim3(32, 2, 8), 256, 0, stream>>>(qkv, Vtm);

  flash2<<<dim3(16, 16, 2), 256, 0, stream>>>(Qm, Km, Vtm, attn);

  gemm_bt<<<dim3(16, 32), 256, 0, stream>>>(attn, WoT, out, 4096, 2048, 2048, 0);
}

// Round 2
// 327.635 us; speedup vs baseline: 1.0224x; 1.0224x over previous
//
#include <hip/hip_runtime.h>
#include <math.h>

// ---------------------------------------------------------------------------
// ByteMultiHeadSelfAttention: B=2 S=2048 E=2048, H=16 KV=4 D=128, RoPE, causal.
//   convx:     x fp32 -> xb bf16
//   wconv_all: Wq|Wk|Wv|Wo fp32 (K,N) -> bf16 (N,K), one launch
//   gemm_bt:   qkv = xb @ Wqkv (bf16)  [DMA double-buffer, single barrier/iter]
//   rope:      Q[B,H,S,D] (pre-scaled by 1/sqrt(D)*log2e), K[B,KV,S,D]
//   vtrans:    Vt[B,KV,D,S]
//   flash2:    32x32 MFMA, swapped QK^T, in-register P (cvt_pk+permlane32_swap),
//              fixed-max softmax, DMA double-buffer, paired q-tiles (uniform 34
//              KV-tiles/block), Q-tile 128/block
//   gemm_bt:   out = attn @ Wo (fp32)
// ---------------------------------------------------------------------------

typedef __attribute__((ext_vector_type(8))) short short8;
typedef __attribute__((ext_vector_type(4))) float f32x4;
typedef __attribute__((ext_vector_type(16))) float f32x16;

typedef const __attribute__((address_space(1))) void* gvp;
typedef __attribute__((address_space(3))) void* svp;

__device__ __forceinline__ void async16(const void* g, void* l) {
  __builtin_amdgcn_global_load_lds((gvp)g, (svp)l, 16, 0, 0);
}
__device__ __forceinline__ void wait_vm0() { asm volatile("s_waitcnt vmcnt(0)" ::: "memory"); }
__device__ __forceinline__ void barrier_raw() { asm volatile("s_barrier" ::: "memory"); }

__device__ __forceinline__ unsigned short f2b(float f) {
  unsigned int u = __builtin_bit_cast(unsigned int, f);
  u += 0x7fffu + ((u >> 16) & 1u);   // RNE
  return (unsigned short)(u >> 16);
}
__device__ __forceinline__ float b2f(unsigned short h) {
  unsigned int u = ((unsigned int)h) << 16;
  return __builtin_bit_cast(float, u);
}

// packed f32->bf16 (RNE, same as f2b) — one instr for two values
__device__ __forceinline__ unsigned int pk_bf16(float a, float b) {
  unsigned int r;
  asm("v_cvt_pk_bf16_f32 %0, %1, %2" : "=v"(r) : "v"(a), "v"(b));
  return r;
}
// exchange a[32..63] <-> b[0..31]
__device__ __forceinline__ void plswap(unsigned int& a, unsigned int& b) {
  asm("v_permlane32_swap_b32 %0, %1" : "+v"(a), "+v"(b));
}

// ---------------- x -> bf16 ----------------
__global__ __launch_bounds__(256) void convx(const float* __restrict__ x,
                                             unsigned short* __restrict__ xb) {
  int i = blockIdx.x * 256 + threadIdx.x;
  const float4* p = (const float4*)x + (size_t)i * 2;
  float4 a = p[0], b4 = p[1];
  union { short8 v; unsigned short u[8]; } o;
  o.u[0] = f2b(a.x);  o.u[1] = f2b(a.y);  o.u[2] = f2b(a.z);  o.u[3] = f2b(a.w);
  o.u[4] = f2b(b4.x); o.u[5] = f2b(b4.y); o.u[6] = f2b(b4.z); o.u[7] = f2b(b4.w);
  ((short8*)xb)[i] = o.v;
}

// ---------------- all W (K,N) fp32 -> WT (N,K) bf16, one launch ----------------
__global__ __launch_bounds__(256) void wconv_all(const float* __restrict__ Wq,
                                                 const float* __restrict__ Wk,
                                                 const float* __restrict__ Wv,
                                                 const float* __restrict__ Wo,
                                                 unsigned short* __restrict__ WqkvT,
                                                 unsigned short* __restrict__ WoT) {
  __shared__ float t[32][33];
  int idx = blockIdx.x;
  const float* W; unsigned short* WT; int N, tx, ty;
  const int K = 2048;
  if (idx < 4096)      { W = Wq; WT = WqkvT;                         N = 2048; idx -= 0;    tx = idx & 63; ty = idx >> 6; }
  else if (idx < 5120) { W = Wk; WT = WqkvT + (size_t)2048 * 2048;   N = 512;  idx -= 4096; tx = idx & 15; ty = idx >> 4; }
  else if (idx < 6144) { W = Wv; WT = WqkvT + (size_t)2560 * 2048;   N = 512;  idx -= 5120; tx = idx & 15; ty = idx >> 4; }
  else                 { W = Wo; WT = WoT;                           N = 2048; idx -= 6144; tx = idx & 63; ty = idx >> 6; }
  int c = threadIdx.x & 31, r0 = threadIdx.x >> 5;
  int k0 = ty * 32, n0 = tx * 32;
#pragma unroll
  for (int r = r0; r < 32; r += 8) t[r][c] = W[(size_t)(k0 + r) * N + n0 + c];
  __syncthreads();
#pragma unroll
  for (int r = r0; r < 32; r += 8) WT[(size_t)(n0 + r) * K + k0 + c] = f2b(t[c][r]);
}

// ---------------- GEMM: C[M,N] = A[M,K] * BT[N,K]^T ----------------
__global__ __launch_bounds__(256) void gemm_bt(const unsigned short* __restrict__ A,
                                               const unsigned short* __restrict__ BT,
                                               void* __restrict__ Cout,
                                               int M, int N, int K, int out_bf16) {
  const int n0 = blockIdx.x * 128;
  const int m0 = blockIdx.y * 128;
  const int tid = threadIdx.x;
  const int w = tid >> 6, lane = tid & 63, l15 = lane & 15, quad = lane >> 4;
  const int wm = w >> 1, wn = w & 1;

  __shared__ __align__(16) unsigned short As[2][128 * 64];
  __shared__ __align__(16) unsigned short Bs[2][128 * 64];

  f32x4 acc[4][4];
#pragma unroll
  for (int mi = 0; mi < 4; mi++)
#pragma unroll
    for (int ni = 0; ni < 4; ni++) acc[mi][ni] = (f32x4){0.f, 0.f, 0.f, 0.f};

  const int rl = lane >> 3;
  const int cl = lane & 7;
  const unsigned short* Ab = A + (size_t)m0 * K;
  const unsigned short* Bb = BT + (size_t)n0 * K;

#pragma unroll
  for (int i = 0; i < 4; i++) {
    int row = w * 32 + i * 8 + rl;
    int gc = cl ^ (row & 7);
    async16(Ab + (size_t)row * K + gc * 8, &As[0][(w * 32 + i * 8) * 64]);
    async16(Bb + (size_t)row * K + gc * 8, &Bs[0][(w * 32 + i * 8) * 64]);
  }

  const int nIter = K >> 6;
  for (int j = 0; j < nIter; j++) {
    wait_vm0();
    barrier_raw();
    const int cur = j & 1;

    if (j + 1 < nIter) {
      int kb = (j + 1) * 64;
#pragma unroll
      for (int i = 0; i < 4; i++) {
        int row = w * 32 + i * 8 + rl;
        int gc = cl ^ (row & 7);
        async16(Ab + (size_t)row * K + kb + gc * 8, &As[cur ^ 1][(w * 32 + i * 8) * 64]);
        async16(Bb + (size_t)row * K + kb + gc * 8, &Bs[cur ^ 1][(w * 32 + i * 8) * 64]);
      }
    }

    const unsigned short* as = &As[cur][0];
    const unsigned short* bs = &Bs[cur][0];
#pragma unroll
    for (int kk = 0; kk < 2; kk++) {
      short8 af[4], bfv[4];
#pragma unroll
      for (int mi = 0; mi < 4; mi++) {
        int row = wm * 64 + mi * 16 + l15;
        af[mi] = *(const short8*)&as[row * 64 + (((kk * 4 + quad) ^ (row & 7)) * 8)];
      }
#pragma unroll
      for (int ni = 0; ni < 4; ni++) {
        int row = wn * 64 + ni * 16 + l15;
        bfv[ni] = *(const short8*)&bs[row * 64 + (((kk * 4 + quad) ^ (row & 7)) * 8)];
      }
#pragma unroll
      for (int mi = 0; mi < 4; mi++)
#pragma unroll
        for (int ni = 0; ni < 4; ni++)
          acc[mi][ni] = __builtin_amdgcn_mfma_f32_16x16x32_bf16(af[mi], bfv[ni],
                                                                acc[mi][ni], 0, 0, 0);
    }
  }

  if (out_bf16) {
    unsigned short* C = (unsigned short*)Cout;
#pragma unroll
    for (int mi = 0; mi < 4; mi++)
#pragma unroll
      for (int ni = 0; ni < 4; ni++)
#pragma unroll
        for (int r = 0; r < 4; r++) {
          int row = m0 + wm * 64 + mi * 16 + quad * 4 + r;
          int col = n0 + wn * 64 + ni * 16 + l15;
          C[(size_t)row * N + col] = f2b(acc[mi][ni][r]);
        }
  } else {
    float* C = (float*)Cout;
#pragma unroll
    for (int mi = 0; mi < 4; mi++)
#pragma unroll
      for (int ni = 0; ni < 4; ni++)
#pragma unroll
        for (int r = 0; r < 4; r++) {
          int row = m0 + wm * 64 + mi * 16 + quad * 4 + r;
          int col = n0 + wn * 64 + ni * 16 + l15;
          C[(size_t)row * N + col] = acc[mi][ni][r];
        }
  }
}

// ---------------- RoPE (Q pre-scaled by 1/sqrt(128)*log2(e)) ----------------
#define SC_TOT 0.12753785056274918f
__global__ __launch_bounds__(256) void rope_kernel(const unsigned short* __restrict__ qkv,
                                                   unsigned short* __restrict__ Q,
                                                   unsigned short* __restrict__ Kd) {
  int b = blockIdx.z, hh = blockIdx.y;
  int tid = threadIdx.x;
  int d = tid & 63, sl = tid >> 6;
  int s = blockIdx.x * 4 + sl;
  const unsigned short* src = qkv + ((size_t)(b * 2048 + s)) * 3072 + hh * 128;
  float lo = b2f(src[d]), hi = b2f(src[d + 64]);
  float invf = exp2f(-0.20762050593046f * (float)d);
  float ang = (float)s * invf;
  float sn, cs;
  sincosf(ang, &sn, &cs);
  float nlo = lo * cs - hi * sn;
  float nhi = hi * cs + lo * sn;
  unsigned short* dst;
  if (hh < 16) {
    nlo *= SC_TOT; nhi *= SC_TOT;
    dst = Q + ((size_t)((b * 16 + hh) * 2048 + s)) * 128;
  } else {
    dst = Kd + ((size_t)((b * 4 + (hh - 16)) * 2048 + s)) * 128;
  }
  dst[d] = f2b(nlo);
  dst[d + 64] = f2b(nhi);
}

// ---------------- V transpose ----------------
__global__ __launch_bounds__(256) void vtrans(const unsigned short* __restrict__ qkv,
                                              unsigned short* __restrict__ Vt) {
  int bkv = blockIdx.z;
  int b = bkv >> 2, kv = bkv & 3;
  int s0 = blockIdx.x * 64, d0 = blockIdx.y * 64;
  __shared__ unsigned short t[64][65];
  int c = threadIdx.x & 63, r0 = threadIdx.x >> 6;
  const unsigned short* src = qkv + ((size_t)(b * 2048 + s0)) * 3072 + 2560 + kv * 128 + d0;
#pragma unroll
  for (int r = r0; r < 64; r += 4) t[r][c] = src[(size_t)r * 3072 + c];
  __syncthreads();
  unsigned short* dst = Vt + ((size_t)bkv * 128 + d0) * 2048 + s0;
#pragma unroll
  for (int r = r0; r < 64; r += 4) dst[(size_t)r * 2048 + c] = t[c][r];
}

// ---------------- Flash attention: 32x32 MFMA, in-register P ----------------
#define FIXED_M 12.0f

// Process one 32(kv)x32(q) S^T accumulator: softmax (fixed max), causal mask,
// l accumulation, and repack into two PV A-fragments (kv 16 each) via
// cvt_pk + permlane32_swap (T12). kvb already includes +4*hi.
__device__ __forceinline__ void proc_acc(const f32x16& s, bool msk, int kvb, int q,
                                         float& l_own, short8& paL, short8& paH) {
  float p[16];
#pragma unroll
  for (int r = 0; r < 16; r++) {
    float v = exp2f(s[r] - FIXED_M);
    if (msk) {
      int kv = kvb + (r & 3) + 8 * (r >> 2);
      if (kv > q) v = 0.f;
    }
    p[r] = v;
    l_own += v;
  }
  unsigned int u0 = pk_bf16(p[0], p[1]),  u1 = pk_bf16(p[2], p[3]);
  unsigned int u2 = pk_bf16(p[4], p[5]),  u3 = pk_bf16(p[6], p[7]);
  plswap(u0, u2); plswap(u1, u3);
  unsigned int w0 = pk_bf16(p[8], p[9]),  w1 = pk_bf16(p[10], p[11]);
  unsigned int w2 = pk_bf16(p[12], p[13]), w3 = pk_bf16(p[14], p[15]);
  plswap(w0, w2); plswap(w1, w3);
  union { unsigned int u[4]; short8 s8; } a, b;
  a.u[0] = u0; a.u[1] = u1; a.u[2] = u2; a.u[3] = u3;
  b.u[0] = w0; b.u[1] = w1; b.u[2] = w2; b.u[3] = w3;
  paL = a.s8; paH = b.s8;
}

__global__ __launch_bounds__(256, 2) void flash2(const unsigned short* __restrict__ Q,
                                                 const unsigned short* __restrict__ Kc,
                                                 const unsigned short* __restrict__ Vt,
                                                 unsigned short* __restrict__ attn) {
  const int pair = blockIdx.x;         // 0..7; block does q-tiles pair and 15-pair
  const int h = blockIdx.y;
  const int b = blockIdx.z;
  const int kvh = h >> 2;
  const int tid = threadIdx.x;
  const int w = tid >> 6, lane = tid & 63;
  const int l31 = lane & 31, hi = lane >> 5, x7 = l31 & 7;

  __shared__ __align__(16) unsigned short kbuf[2][64 * 128];   // [kv][d] swz
  __shared__ __align__(16) unsigned short vbuf[2][128 * 64];   // [d][s]  swz
  __shared__ __align__(16) float li[4][32];

  const unsigned short* Qb = Q  + ((size_t)(b * 16 + h)) * 2048 * 128;
  const unsigned short* Kb = Kc + ((size_t)(b * 4 + kvh)) * 2048 * 128;
  const unsigned short* Vb = Vt + ((size_t)(b * 4 + kvh)) * 128 * 2048;

  for (int t = 0; t < 2; t++) {
    const int qt = (t == 0) ? pair : (15 - pair);   // uniform: 34 KV-tiles/block
    const int q0 = qt * 128;
    const int qw = q0 + w * 32;        // wave's q base (32 rows)
    const int qv = qw + l31;           // this lane's q row
    const int nT = 2 * qt + 2;

    // Q fragments: qf[s] = Q[qv][s*16 + hi*8 .. +7]
    short8 qf[8];
    {
      const unsigned short* qp = Qb + (size_t)qv * 128 + hi * 8;
#pragma unroll
      for (int s = 0; s < 8; s++) qf[s] = *(const short8*)(qp + s * 16);
    }

    f32x16 o[4];
#pragma unroll
    for (int d = 0; d < 4; d++)
#pragma unroll
      for (int e = 0; e < 16; e++) o[d][e] = 0.f;
    float l_own = 0.f;

    barrier_raw();   // pass 2: all waves done reading bufs from pass 1

    // prologue: DMA tile 0 into buf 0
#pragma unroll
    for (int k2 = 0; k2 < 4; k2++) {
      int m = w * 4 + k2;
      int rl = m * 4 + (lane >> 4);
      int c8 = (lane & 15) ^ (rl & 7);
      async16(Kb + (size_t)rl * 128 + c8 * 8, &kbuf[0][m * 512]);
    }
#pragma unroll
    for (int k2 = 0; k2 < 4; k2++) {
      int m = w * 4 + k2;
      int d = m * 8 + (lane >> 3);
      int c3 = (lane & 7) ^ (d & 7);
      async16(Vb + (size_t)d * 2048 + c3 * 8, &vbuf[0][m * 512]);
    }

    for (int j = 0; j < nT; j++) {
      wait_vm0();
      barrier_raw();
      const int cur = j & 1;
      const int kb = j * 64;

      if (j + 1 < nT) {
        int kb2 = kb + 64;
#pragma unroll
        for (int k2 = 0; k2 < 4; k2++) {
          int m = w * 4 + k2;
          int rl = m * 4 + (lane >> 4);
          int c8 = (lane & 15) ^ (rl & 7);
          async16(Kb + (size_t)(kb2 + rl) * 128 + c8 * 8, &kbuf[cur ^ 1][m * 512]);
        }
#pragma unroll
        for (int k2 = 0; k2 < 4; k2++) {
          int m = w * 4 + k2;
          int d = m * 8 + (lane >> 3);
          int c3 = (lane & 7) ^ (d & 7);
          async16(Vb + (size_t)d * 2048 + kb2 + c3 * 8, &vbuf[cur ^ 1][m * 512]);
        }
      }

      if (kb > qw + 31) continue;      // tile fully above diagonal for this wave

      // QK^T swapped: S^T[kv, q] = mfma(A=K, B=Q), two 32-kv blocks
      f32x16 sA, sB;
#pragma unroll
      for (int e = 0; e < 16; e++) { sA[e] = 0.f; sB[e] = 0.f; }
      const unsigned short* kp = &kbuf[cur][0];
      __builtin_amdgcn_s_setprio(1);
#pragma unroll
      for (int s = 0; s < 8; s++) {
        int ch = (((s << 1) | hi) ^ x7) << 3;
        short8 ka = *(const short8*)&kp[l31 * 128 + ch];
        short8 kB = *(const short8*)&kp[(32 + l31) * 128 + ch];
        sA = __builtin_amdgcn_mfma_f32_32x32x16_bf16(ka, qf[s], sA, 0, 0, 0);
        sB = __builtin_amdgcn_mfma_f32_32x32x16_bf16(kB, qf[s], sB, 0, 0, 0);
      }
      __builtin_amdgcn_s_setprio(0);

      const bool msk = (kb + 63 > qw);
      short8 pa[4];
      proc_acc(sA, msk, kb + 4 * hi, qv, l_own, pa[0], pa[1]);
      proc_acc(sB, msk, kb + 32 + 4 * hi, qv, l_own, pa[2], pa[3]);

      // PV: O[q, d] += P * V ; V from [d][s] LDS rows, contiguous b128 B-frags
      const unsigned short* vp = &vbuf[cur][0];
      __builtin_amdgcn_s_setprio(1);
#pragma unroll
      for (int db = 0; db < 4; db++) {
        int ro = (db * 32 + l31) * 64;
#pragma unroll
        for (int f = 0; f < 4; f++) {
          int ch = (((f << 1) | hi) ^ x7) << 3;
          short8 vf = *(const short8*)&vp[ro + ch];
          o[db] = __builtin_amdgcn_mfma_f32_32x32x16_bf16(pa[f], vf, o[db], 0, 0, 0);
        }
      }
      __builtin_amdgcn_s_setprio(0);
    }

    // normalize: l per q row lives at lane (q, hi) + (q, hi^1)
    float l_tot = l_own + __shfl_xor(l_own, 32);
    if (hi == 0) li[w][l31] = 1.f / l_tot;
    f32x4 inv4[4];
#pragma unroll
    for (int tt = 0; tt < 4; tt++) inv4[tt] = *(const f32x4*)&li[w][tt * 8 + 4 * hi];

    // O C-layout: col(lane)=d=db*32+l31, row(reg)=(r&3)+8*(r>>2)+4*hi
    unsigned short* ap0 = attn + ((size_t)(b * 2048 + qw)) * 2048 + h * 128 + l31;
#pragma unroll
    for (int db = 0; db < 4; db++) {
#pragma unroll
      for (int r = 0; r < 16; r++) {
        int rowq = (r & 3) + 8 * (r >> 2) + 4 * hi;
        ap0[(size_t)rowq * 2048 + db * 32] = f2b(o[db][r] * inv4[r >> 2][r & 3]);
      }
    }
  }
}

// ---------------------------------------------------------------------------
extern "C" void kernel_launch(void* const* d_in, const int* in_sizes, int n_in,
                              void* d_out, int out_size, void* d_ws, size_t ws_size,
                              hipStream_t stream) {
  const float* x  = (const float*)d_in[0];
  const float* Wq = (const float*)d_in[1];
  const float* Wk = (const float*)d_in[2];
  const float* Wv = (const float*)d_in[3];
  const float* Wo = (const float*)d_in[4];
  float* out = (float*)d_out;

  char* ws = (char*)d_ws;
  unsigned short* xb    = (unsigned short*)(ws);              // 16.78 MB (reused as attn)
  unsigned short* WqkvT = (unsigned short*)(ws + 16777216);   // 12.58 MB [3072][2048]
  unsigned short* WoT   = (unsigned short*)(ws + 29360128);   //  8.39 MB [2048][2048]
  unsigned short* qkv   = (unsigned short*)(ws + 37748736);   // 25.17 MB [4096][3072]
  unsigned short* Qm    = (unsigned short*)(ws + 62914560);   // 16.78 MB [B,H,S,D]
  unsigned short* Km    = (unsigned short*)(ws + 79691776);   //  4.19 MB [B,KV,S,D]
  unsigned short* Vtm   = (unsigned short*)(ws + 83886080);   //  4.19 MB [B,KV,D,S]
  unsigned short* attn  = xb;

  convx<<<4096, 256, 0, stream>>>(x, xb);
  wconv_all<<<10240, 256, 0, stream>>>(Wq, Wk, Wv, Wo, WqkvT, WoT);

  gemm_bt<<<dim3(24, 32), 256, 0, stream>>>(xb, WqkvT, qkv, 4096, 3072, 2048, 1);

  rope_kernel<<<dim3(512, 20, 2), 256, 0, stream>>>(qkv, Qm, Km);
  vtrans<<<dim3(32, 2, 8), 256, 0, stream>>>(qkv, Vtm);

  flash2<<<dim3(8, 16, 2), 256, 0, stream>>>(Qm, Km, Vtm, attn);

  gemm_bt<<<dim3(16, 32), 256, 0, stream>>>(attn, WoT, out, 4096, 2048, 2048, 0);
}